// Round 1
// baseline (551.138 us; speedup 1.0000x reference)
//
#include <hip/hip_runtime.h>

#define NN 256
#define CC 64
#define TT 64
#define VV 25
#define SS 3
#define RR 8
#define OO 64
#define HH 16

typedef _Float16 f16;
typedef _Float16 f16x8 __attribute__((ext_vector_type(8)));
typedef float f32x4 __attribute__((ext_vector_type(4)));

#define IBN 0.9999950000374997f   /* 1/sqrt(1+1e-5) */

// ---------------------------------------------------------------------------
// Kernel AB: per-n preprocessing.
//  - xm[c][v] = mean_t x[n,c,t,v]
//  - x1/x2 (1x1 convs on xm), att = tanh(x1[u]-x2[v]) -> ws (f16)
//  - SE gate se[n,o] computed analytically (softmax rows sum to 1 => pooled
//    depends only on xm), BN folded in.
//  - block 0 additionally packs Asym = PA+PA^T and w3 in MFMA A-frag order.
// ---------------------------------------------------------------------------
__global__ __launch_bounds__(256) void kab(
    const float* __restrict__ x, const float* __restrict__ PA,
    const float* __restrict__ w1, const float* __restrict__ b1,
    const float* __restrict__ w2, const float* __restrict__ b2,
    const float* __restrict__ w3, const float* __restrict__ b3,
    const float* __restrict__ bn_w, const float* __restrict__ bn_b,
    const float* __restrict__ se_w1, const float* __restrict__ se_b1,
    const float* __restrict__ se_w2, const float* __restrict__ se_b2,
    f16* __restrict__ atts_g, float* __restrict__ se_g,
    float* __restrict__ asym_g, f16* __restrict__ w3p_g)
{
  __shared__ float slab[4*1616];     // 4 c-slabs, padded stride vs bank conflicts
  __shared__ float xms[CC*VV];
  __shared__ float x1s[600], x2s[600];
  __shared__ float w1s[1536], w2s[1536];
  __shared__ float xmv[CC], pooledv[OO], hbuf[HH];

  int n = blockIdx.x, tid = threadIdx.x;

  for (int i = tid; i < 1536; i += 256) { w1s[i] = w1[i]; w2s[i] = w2[i]; }

  // xm = mean over T
  for (int cg = 0; cg < 16; ++cg) {
    __syncthreads();
    #pragma unroll
    for (int it = 0; it < 25; ++it) {
      int idx = it*256 + tid;                 // < 6400
      int c4 = idx / 1600, r = idx - c4*1600;
      slab[c4*1616 + r] = x[(n*CC + cg*4 + c4)*1600 + r];
    }
    __syncthreads();
    if (tid < 100) {
      int c4 = tid / 25, v = tid - c4*25;
      float s = 0.f;
      #pragma unroll
      for (int t = 0; t < 64; ++t) s += slab[c4*1616 + t*25 + v];
      xms[(cg*4 + c4)*25 + v] = s * (1.0f/64.0f);
    }
  }
  __syncthreads();

  // x1/x2: [S*R, V]
  for (int idx = tid; idx < 600; idx += 256) {
    int sr = idx / 25, v = idx - sr*25;
    float a1 = b1[sr], a2 = b2[sr];
    for (int c = 0; c < 64; ++c) {
      float xv = xms[c*25 + v];
      a1 += xv * w1s[sr*64 + c];
      a2 += xv * w2s[sr*64 + c];
    }
    x1s[idx] = a1; x2s[idx] = a2;
  }
  __syncthreads();

  // att = tanh(x1[u] - x2[v]) -> global f16
  for (int idx = tid; idx < 15000; idx += 256) {
    int sr = idx / 625, rem = idx - sr*625;
    int u = rem / 25, v = rem - u*25;
    atts_g[n*15000 + idx] = (f16)tanhf(x1s[sr*25 + u] - x2s[sr*25 + v]);
  }

  // SE gate (BN folded). pooled = sum_c xmv[c]*sum_s w3[s,o,c] + sum_s b3[s,o]
  if (tid < 64) {
    float s = 0.f;
    #pragma unroll
    for (int v = 0; v < 25; ++v) s += xms[tid*25 + v];
    xmv[tid] = s * (1.0f/25.0f);
  }
  __syncthreads();
  if (tid < 64) {
    int o = tid;
    float p = b3[o] + b3[64 + o] + b3[128 + o];
    for (int c = 0; c < 64; ++c)
      p += xmv[c] * (w3[o*64 + c] + w3[4096 + o*64 + c] + w3[8192 + o*64 + c]);
    pooledv[o] = IBN * bn_w[o] * p + bn_b[o];
  }
  __syncthreads();
  if (tid < 16) {
    float hh = se_b1[tid];
    for (int o = 0; o < 64; ++o) hh += pooledv[o] * se_w1[tid*64 + o];
    hbuf[tid] = fmaxf(hh, 0.0f);
  }
  __syncthreads();
  if (tid < 64) {
    float t = se_b2[tid];
    for (int j = 0; j < 16; ++j) t += hbuf[j] * se_w2[tid*16 + j];
    se_g[n*64 + tid] = 1.0f / (1.0f + __expf(-t));
  }

  if (n == 0) {
    for (int idx = tid; idx < 1875; idx += 256) {
      int s = idx / 625, rem = idx - s*625, u = rem / 25, v = rem - u*25;
      asym_g[idx] = PA[s*625 + u*25 + v] + PA[s*625 + v*25 + u];
    }
    // pack w3 into MFMA A-fragment order:
    // w3p[((mi*2+kk)*64+lane)*8+j] = w3[m=mi*16+(lane&15)][c=kk*32+(lane>>4)*8+j]
    for (int idx = tid; idx < 12288; idx += 256) {
      int j = idx & 7, lane = (idx >> 3) & 63, kk = (idx >> 9) & 1, mi = idx >> 10;
      int s = mi >> 2, o = ((mi & 3) << 4) + (lane & 15);
      int c = kk*32 + ((lane >> 4) << 3) + j;
      w3p_g[idx] = (f16)w3[(s*64 + o)*64 + c];
    }
  }
}

// ---------------------------------------------------------------------------
// Kernel C: per (n, t-tile of 16). MFMA f16 pipeline:
//  stage1: Z[16 so][16t x 25v] = W3 * X + b3         (16x16x32 f16 MFMA)
//  m: m_pre = (att . w4 + b4)*alpha + Asym ; softmax over u (in-place f16)
//  stage2: Y[t][u] += Z[t][v] * m[u][v]              (K=25 zero-padded to 32)
//  epilogue: out = relu(Y*ibn*bn_w*se + bn_b*se + x) (residual from LDS tile)
// ---------------------------------------------------------------------------
struct __align__(16) SmemC {
  f16   xsT[400][72];      // X tile transposed [j=t*25+v][c], pad 72 (2-way free)
  f16   zs[16][16][40];    // Z  [o'][t][v], row pad 40 (16B-aligned, 2-way free)
  f16   ms[16][25][40];    // m  [o'][u][v]
  f16   atts[3*8*625];     // att[s][r][u*25+v]
  float asym[3*625];
  float b3s[192];
};                          // 148,348 B

__global__ __launch_bounds__(256) void kc(
    const float* __restrict__ x,
    const float* __restrict__ alpha, const float* __restrict__ b3,
    const float* __restrict__ w4, const float* __restrict__ b4,
    const float* __restrict__ bn_w, const float* __restrict__ bn_b,
    const f16* __restrict__ atts_g, const float* __restrict__ se_g,
    const float* __restrict__ asym_g, const f16* __restrict__ w3p_g,
    float* __restrict__ out)
{
  __shared__ SmemC sm;
  int bid = blockIdx.x;
  int n = bid >> 2, tt = bid & 3;
  int tid = threadIdx.x;
  int lane = tid & 63, w = tid >> 6, q = lane >> 4, l15 = lane & 15;

  // ---- preamble: stage X tile (transposed, f16), att, asym, b3; zero K-pads
  {
    const float* xb = x + (size_t)n*CC*1600 + tt*400;
    #pragma unroll
    for (int it = 0; it < 50; ++it) {
      int idx = it*256 + tid;                 // < 12800 (c-pairs x j)
      int cp = idx / 400, j = idx - cp*400;
      float v0 = xb[(2*cp)*1600 + j];
      float v1 = xb[(2*cp + 1)*1600 + j];
      f16* p = &sm.xsT[j][2*cp];
      p[0] = (f16)v0; p[1] = (f16)v1;
    }
    const unsigned* ag = (const unsigned*)(atts_g + n*15000);
    unsigned* al = (unsigned*)sm.atts;
    for (int i = tid; i < 7500; i += 256) al[i] = ag[i];
    for (int i = tid; i < 1875; i += 256) sm.asym[i] = asym_g[i];
    if (tid < 192) sm.b3s[tid] = b3[tid];
    // zero zs cols v=25..39 (stage2 A-side K-pad must be 0; never rewritten)
    for (int i = tid; i < 3840; i += 256) {
      int op = i / 240, rem = i - op*240, t = rem / 15, v = 25 + (rem - t*15);
      sm.zs[op][t][v] = (f16)0.f;
    }
    // zero ms cols v=25..39 (avoid NaN garbage in B-frags)
    for (int i = tid; i < 6000; i += 256) {
      int op = i / 375, rem = i - op*375, u = rem / 15, v = 25 + (rem - u*15);
      sm.ms[op][u][v] = (f16)0.f;
    }
  }
  __syncthreads();

  const f16x8* w3pv = (const f16x8*)w3p_g;

  for (int ob = 0; ob < 4; ++ob) {
    f32x4 yacc[4][2];
    #pragma unroll
    for (int i = 0; i < 4; ++i) {
      yacc[i][0] = (f32x4){0.f,0.f,0.f,0.f};
      yacc[i][1] = (f32x4){0.f,0.f,0.f,0.f};
    }

    for (int s = 0; s < 3; ++s) {
      __syncthreads();   // protect ms/zs vs previous stage2

      // ---- pass1: m_pre -> ms (pre-softmax).  w4/b4 via scalar loads.
      {
        float alphav = alpha[s];
        #pragma unroll
        for (int e = 0; e < 3; ++e) {
          int uv = tid + e*256;
          if (uv < 625) {
            int u = uv / 25, v = uv - u*25;
            float attv[8];
            #pragma unroll
            for (int r = 0; r < 8; ++r) attv[r] = (float)sm.atts[(s*8 + r)*625 + uv];
            float asv = sm.asym[s*625 + uv];
            #pragma unroll
            for (int oc = 0; oc < 4; ++oc) {
              #pragma unroll
              for (int oi = 0; oi < 4; ++oi) {
                int op = oc*4 + oi;
                int o = ob*16 + op;
                float acc = b4[s*64 + o];
                #pragma unroll
                for (int r = 0; r < 8; ++r) acc += attv[r] * w4[(s*64 + o)*8 + r];
                sm.ms[op][u][v] = (f16)(acc*alphav + asv);
              }
            }
          }
        }
      }

      // ---- stage1: Z = W3*X + b3 -> zs
      {
        int mi = s*4 + ob;
        f16x8 a0 = w3pv[(mi*2 + 0)*64 + lane];
        f16x8 a1 = w3pv[(mi*2 + 1)*64 + lane];
        for (int ni = w; ni < 25; ni += 4) {
          int row = ni*16 + l15;              // j = t*25+v  (also D n-col)
          f16x8 bf0 = *(const f16x8*)&sm.xsT[row][q*8];
          f16x8 bf1 = *(const f16x8*)&sm.xsT[row][32 + q*8];
          f32x4 acc = (f32x4){0.f,0.f,0.f,0.f};
          acc = __builtin_amdgcn_mfma_f32_16x16x32_f16(a0, bf0, acc, 0, 0, 0);
          acc = __builtin_amdgcn_mfma_f32_16x16x32_f16(a1, bf1, acc, 0, 0, 0);
          int t = row / 25, v = row - t*25;
          #pragma unroll
          for (int rg = 0; rg < 4; ++rg) {
            int op = q*4 + rg;                // D m-row = o'
            sm.zs[op][t][v] = (f16)(acc[rg] + sm.b3s[s*64 + ob*16 + op]);
          }
        }
      }
      __syncthreads();

      // ---- pass2: softmax over u, in place on ms
      #pragma unroll
      for (int e = 0; e < 2; ++e) {
        int col = tid + e*256;
        if (col < 400) {
          int op = col / 25, v = col - op*25;
          float vals[25]; float mx = -1e30f;
          #pragma unroll
          for (int u = 0; u < 25; ++u) {
            float t2 = (float)sm.ms[op][u][v];
            vals[u] = t2; mx = fmaxf(mx, t2);
          }
          float sum = 0.f;
          #pragma unroll
          for (int u = 0; u < 25; ++u) { float ev = __expf(vals[u] - mx); vals[u] = ev; sum += ev; }
          float inv = 1.0f / sum;
          #pragma unroll
          for (int u = 0; u < 25; ++u) sm.ms[op][u][v] = (f16)(vals[u]*inv);
        }
      }
      __syncthreads();

      // ---- stage2: Y[t][u] += Z[t][v] * m[u][v]   (one K=32 MFMA per u-tile)
      #pragma unroll
      for (int i = 0; i < 4; ++i) {
        int op = w*4 + i;
        f16x8 az  = *(const f16x8*)&sm.zs[op][l15][q*8];       // A[t][v]
        f16x8 bm0 = *(const f16x8*)&sm.ms[op][l15][q*8];       // B[v][u] = m[u][v]
        int u2 = 16 + l15; if (u2 > 24) u2 = 24;               // clamp, cols discarded
        f16x8 bm1 = *(const f16x8*)&sm.ms[op][u2][q*8];
        yacc[i][0] = __builtin_amdgcn_mfma_f32_16x16x32_f16(az, bm0, yacc[i][0], 0, 0, 0);
        yacc[i][1] = __builtin_amdgcn_mfma_f32_16x16x32_f16(az, bm1, yacc[i][1], 0, 0, 0);
      }
    }

    // ---- epilogue for this o-block: BN+SE+residual+ReLU
    #pragma unroll
    for (int i = 0; i < 4; ++i) {
      int op = w*4 + i, o = ob*16 + op;
      float sev   = se_g[n*64 + o];
      float scale = IBN * bn_w[o] * sev;
      float bias  = bn_b[o] * sev;
      #pragma unroll
      for (int ut = 0; ut < 2; ++ut) {
        int u = ut*16 + l15;
        if (u < 25) {
          #pragma unroll
          for (int rg = 0; rg < 4; ++rg) {
            int t = q*4 + rg;                                   // D m-row = t
            float xres = (float)sm.xsT[t*25 + u][o];
            float val = yacc[i][ut][rg]*scale + bias + xres;
            out[(((size_t)n*64 + o)*64 + tt*16 + t)*25 + u] = fmaxf(val, 0.0f);
          }
        }
      }
    }
  }
}

// ---------------------------------------------------------------------------
extern "C" void kernel_launch(void* const* d_in, const int* in_sizes, int n_in,
                              void* d_out, int out_size, void* d_ws, size_t ws_size,
                              hipStream_t stream)
{
  const float* x    = (const float*)d_in[0];
  const float* PA   = (const float*)d_in[1];
  const float* alp  = (const float*)d_in[2];
  const float* w1   = (const float*)d_in[3];
  const float* b1   = (const float*)d_in[4];
  const float* w2   = (const float*)d_in[5];
  const float* b2   = (const float*)d_in[6];
  const float* w3   = (const float*)d_in[7];
  const float* b3   = (const float*)d_in[8];
  const float* w4   = (const float*)d_in[9];
  const float* b4   = (const float*)d_in[10];
  const float* bnw  = (const float*)d_in[11];
  const float* bnb  = (const float*)d_in[12];
  const float* sw1  = (const float*)d_in[13];
  const float* sb1  = (const float*)d_in[14];
  const float* sw2  = (const float*)d_in[15];
  const float* sb2  = (const float*)d_in[16];

  char* ws = (char*)d_ws;
  f16*   atts_g = (f16*)ws;                      // 3,840,000 f16 = 7,680,000 B
  float* se_g   = (float*)(ws + 7680000);        // 16,384 floats
  float* asym_g = (float*)(ws + 7745536);        // 1,875 floats
  f16*   w3p_g  = (f16*)(ws + 7753216);          // 12,288 f16 (16B aligned)

  float* out = (float*)d_out;

  kab<<<256, 256, 0, stream>>>(x, PA, w1, b1, w2, b2, w3, b3, bnw, bnb,
                               sw1, sb1, sw2, sb2, atts_g, se_g, asym_g, w3p_g);
  kc<<<1024, 256, 0, stream>>>(x, alp, b3, w4, b4, bnw, bnb,
                               atts_g, se_g, asym_g, w3p_g, out);
}